// Round 1
// baseline (471.721 us; speedup 1.0000x reference)
//
#include <hip/hip_runtime.h>
#include <cstdint>
#include <cstddef>

#define S_LEN 2048
#define DIM_   2048
#define NH   16
#define NKV  8
#define HD   128

typedef __attribute__((ext_vector_type(8))) __bf16 bf16x8;
typedef __attribute__((ext_vector_type(4))) float  f32x4;

typedef const __attribute__((address_space(1))) void* gptr_t;
typedef __attribute__((address_space(3))) void*       sptr_t;

static __device__ __forceinline__ float bf2f(unsigned short u) {
  union { unsigned int i; float f; } v; v.i = ((unsigned int)u) << 16; return v.f;
}
static __device__ __forceinline__ unsigned short f2bf(float f) {
  union { float f; unsigned int i; } v; v.f = f;
  unsigned int u = v.i;
  unsigned int r = (u + 0x7FFFu + ((u >> 16) & 1u)) >> 16;
  return (unsigned short)r;
}

// scale(1/sqrt(128)) * log2(e) — folded into q so softmax uses exp2 directly
#define QSCALE 0.12751744f
// defer-max threshold (T13): 8 in ln-domain -> 8*log2(e) in exp2-domain
#define RESC_THR 11.542f

// ---------------- prep: x->bf16 convert + 4 weight transpose-converts ----------------
__global__ void k_prep(const float* __restrict__ x, unsigned short* __restrict__ xb,
                       const float* __restrict__ wq, const float* __restrict__ wk,
                       const float* __restrict__ wv, const float* __restrict__ wo,
                       unsigned short* __restrict__ wqkvT, unsigned short* __restrict__ woT) {
  int bid = blockIdx.x;
  if (bid < 8192) {
    int i = bid * 256 + threadIdx.x;
    float4 v = ((const float4*)x)[i];
    ushort4 o; o.x = f2bf(v.x); o.y = f2bf(v.y); o.z = f2bf(v.z); o.w = f2bf(v.w);
    ((ushort4*)xb)[i] = o;
    return;
  }
  bid -= 8192;
  const float* src; unsigned short* dst; int N, ntx;
  if (bid < 4096)      { src = wq; dst = wqkvT;                       N = 2048; ntx = 64; }
  else if (bid < 6144) { bid -= 4096; src = wk; dst = wqkvT + (size_t)2048 * 2048; N = 1024; ntx = 32; }
  else if (bid < 8192) { bid -= 6144; src = wv; dst = wqkvT + (size_t)3072 * 2048; N = 1024; ntx = 32; }
  else                 { bid -= 8192; src = wo; dst = woT;            N = 2048; ntx = 64; }
  const int K = 2048;
  __shared__ float tile[32][33];
  int lx = threadIdx.x & 31, ly = threadIdx.x >> 5; // 32 x 8
  int r0 = (bid / ntx) * 32, c0 = (bid % ntx) * 32;
  #pragma unroll
  for (int r = 0; r < 32; r += 8)
    tile[ly + r][lx] = src[(size_t)(r0 + ly + r) * N + c0 + lx];
  __syncthreads();
  #pragma unroll
  for (int r = 0; r < 32; r += 8)
    dst[(size_t)(c0 + ly + r) * K + r0 + lx] = f2bf(tile[lx][ly + r]);
}

// ------------- GEMM: C(MxN) = A(MxK) * BT(NxK)^T, bf16 in, fp32 acc -------------
// BK=64, XOR-swizzled LDS via source permutation (conflict-free, measured 0).
// __launch_bounds__(256,2): VGPR cap 256 so all fragments stay live.
// MODE 1: store f32 natural C[m][n]
// MODE 3: fused QKV epilogue (q+RoPE*QSCALE | k+RoPE | v transposed).
template<int MODE>
__global__ __launch_bounds__(256, 2) void k_gemm_bt(
    const unsigned short* __restrict__ A, const unsigned short* __restrict__ BT,
    void* __restrict__ C, int N, int K,
    const float* __restrict__ fc, const float* __restrict__ fs,
    unsigned short* __restrict__ kb, unsigned short* __restrict__ vb) {
  __shared__ __align__(16) unsigned short Asm[128 * 64];
  __shared__ __align__(16) unsigned short Bsm[128 * 64];
  const int t = threadIdx.x;
  const int lane = t & 63, w = t >> 6;
  const int wm = (w >> 1) * 64, wn = (w & 1) * 64;
  const int col = lane & 15, quad = lane >> 4;
  const int m0 = blockIdx.y * 128, n0 = blockIdx.x * 128;

  f32x4 acc[4][4];
  #pragma unroll
  for (int i = 0; i < 4; i++)
    #pragma unroll
    for (int j = 0; j < 4; j++) acc[i][j] = (f32x4){0.f, 0.f, 0.f, 0.f};

  for (int kk = 0; kk < K; kk += 64) {
    #pragma unroll
    for (int r = 0; r < 4; ++r) {
      int c = t + r * 256;
      int c0 = (t & ~63) + r * 256;   // wave-uniform chunk base
      int row = c >> 3;
      int kcs = (c & 7) ^ (row & 7);  // source permutation = target swizzle
      const unsigned short* gA = A + (size_t)(m0 + row) * K + kk + kcs * 8;
      const unsigned short* gB = BT + (size_t)(n0 + row) * K + kk + kcs * 8;
      __builtin_amdgcn_global_load_lds((gptr_t)gA, (sptr_t)(&Asm[c0 * 8]), 16, 0, 0);
      __builtin_amdgcn_global_load_lds((gptr_t)gB, (sptr_t)(&Bsm[c0 * 8]), 16, 0, 0);
    }
    __syncthreads();
    #pragma unroll
    for (int kc2 = 0; kc2 < 2; kc2++) {
      bf16x8 af[4], bf[4];
      #pragma unroll
      for (int mi = 0; mi < 4; mi++) {
        int rowA = wm + mi * 16 + col;
        af[mi] = *(const bf16x8*)(&Asm[rowA * 64 + (((kc2 * 4 + quad) ^ (col & 7)) * 8)]);
      }
      #pragma unroll
      for (int ni = 0; ni < 4; ni++) {
        int rowB = wn + ni * 16 + col;
        bf[ni] = *(const bf16x8*)(&Bsm[rowB * 64 + (((kc2 * 4 + quad) ^ (col & 7)) * 8)]);
      }
      #pragma unroll
      for (int mi = 0; mi < 4; mi++)
        #pragma unroll
        for (int ni = 0; ni < 4; ni++)
          acc[mi][ni] = __builtin_amdgcn_mfma_f32_16x16x32_bf16(af[mi], bf[ni], acc[mi][ni], 0, 0, 0);
    }
    __syncthreads();
  }

  #pragma unroll
  for (int mi = 0; mi < 4; mi++) {
    int row_base = m0 + wm + mi * 16 + quad * 4;
    #pragma unroll
    for (int ni = 0; ni < 4; ni++) {
      int col_g = n0 + wn + ni * 16 + col;
      if (MODE == 1) {
        float* O = (float*)C;
        #pragma unroll
        for (int r = 0; r < 4; r++) O[(size_t)(row_base + r) * N + col_g] = acc[mi][ni][r];
      } else {  // MODE 3
        int region = col_g >> 10;  // 0,1: q ; 2: k ; 3: v
        if (region < 3) {
          int ri = (col_g & 127) >> 1;
          float sgn = (col_g & 1) ? 1.f : -1.f;
          unsigned short* qO = (unsigned short*)C;
          #pragma unroll
          for (int r = 0; r < 4; r++) {
            int row = row_base + r;
            int s = row & (S_LEN - 1);
            float cv = fc[s * 64 + ri], sv = fs[s * 64 + ri];
            float val = acc[mi][ni][r];
            float other = __shfl_xor(val, 1);
            float res = val * cv + sgn * other * sv;
            if (region < 2) qO[(size_t)row * 2048 + col_g] = f2bf(res * QSCALE);
            else            kb[(size_t)row * 1024 + (col_g - 2048)] = f2bf(res);
          }
        } else {
          int n_local = col_g - 3072;
          int b = row_base >> 11, s = row_base & (S_LEN - 1);
          int kvh = n_local >> 7, d = n_local & (HD - 1);
          ushort4 o4;
          o4.x = f2bf(acc[mi][ni][0]); o4.y = f2bf(acc[mi][ni][1]);
          o4.z = f2bf(acc[mi][ni][2]); o4.w = f2bf(acc[mi][ni][3]);
          *(ushort4*)(&vb[((size_t)((b * NKV + kvh) * HD + d)) * S_LEN + s]) = o4;
        }
      }
    }
  }
}

// ---------------- Flash attention, causal, GQA-shared K/V ----------------
// RESTRUCTURED: 512-thread blocks (8 waves = 2 heads x 4 waves), ONE q-tile per
// block. LDS 53 KB -> 2-3 independent blocks co-resident per CU (vs 1x1024 with
// a single barrier domain). Co-resident blocks are phase-decorrelated, so one
// block's QK/PV MFMAs overlap another's softmax/staging latency. Causal range
// is now wave-uniform (nkt = y+1): no idle waves. Balanced dispatch: yi<16 ? yi
// : 47-yi pairs long and short q-tiles across co-scheduled blocks (sum = 33).
// Plus T5 setprio around MFMA clusters and T13 defer-max (skip O-rescale while
// tile max grows < RESC_THR; P <= 2^11.5, pure scaling, normalized by l at end).
#define KLD 136   // 128 + 8 (row-to-row bank offset 4 -> conflict-free frags)
#define VLD 72    // 64 + 8
__global__ __launch_bounds__(512, 6) void k_attn(
    const unsigned short* __restrict__ q, const unsigned short* __restrict__ k,
    const unsigned short* __restrict__ vT, unsigned short* __restrict__ ao) {
  __shared__ __align__(16) unsigned short Ksm[64 * KLD];       // 17408 B
  __shared__ __align__(16) unsigned short Vsm[128 * VLD];      // 18432 B
  __shared__ __align__(16) unsigned short Psm[8 * 16 * VLD];   // 18432 B
  const int t = threadIdx.x;
  const int lane = t & 63, w = t >> 6;        // 8 waves
  const int col = lane & 15, quad = lane >> 4;
  const int g = blockIdx.x;                   // b*NKV + kvh
  const int b = g >> 3, kvh = g & 7;
  const int h = kvh * 2 + (w >> 2);           // waves 0-3: head 2g, 4-7: head 2g+1
  const int yi = blockIdx.y;                  // 0..31
  const int my_qt = (yi < 16) ? yi : 47 - yi; // balanced long/short pairing
  const int qrow = my_qt * 64 + (w & 3) * 16; // this wave's 16 query rows
  unsigned short* Pw = &Psm[w * 16 * VLD];

  bf16x8 qf[4];
  const size_t qbase = ((size_t)(b * S_LEN) + qrow + col) * DIM_ + h * HD;
  #pragma unroll
  for (int kc = 0; kc < 4; kc++) qf[kc] = *(const bf16x8*)(q + qbase + kc * 32 + quad * 8);

  f32x4 o[8];
  #pragma unroll
  for (int i = 0; i < 8; i++) o[i] = (f32x4){0.f, 0.f, 0.f, 0.f};
  float m_i[4] = {-1e30f, -1e30f, -1e30f, -1e30f};
  float l_i[4] = {0.f, 0.f, 0.f, 0.f};

  const int nkt = my_qt + 1;                  // wave-uniform causal range
  for (int kt = 0; kt < nkt; ++kt) {
    // stage K tile (64 keys x 128 d) and V^T tile (128 d x 64 keys):
    // 2 uint4 per thread per matrix (512 threads)
    #pragma unroll
    for (int cc = 0; cc < 2; cc++) {
      int c = t + cc * 512;
      int i = c >> 4, dc = c & 15;
      *(uint4*)(&Ksm[i * KLD + dc * 8]) =
          *(const uint4*)(k + ((size_t)(b * S_LEN + kt * 64 + i)) * (NKV * HD) + kvh * HD + dc * 8);
    }
    #pragma unroll
    for (int cc = 0; cc < 2; cc++) {
      int c = t + cc * 512;
      int d = c >> 3, kc2 = c & 7;
      *(uint4*)(&Vsm[d * VLD + kc2 * 8]) =
          *(const uint4*)(vT + ((size_t)((b * NKV + kvh) * HD + d)) * S_LEN + kt * 64 + kc2 * 8);
    }
    __syncthreads();

    float p[4][4];
    __builtin_amdgcn_s_setprio(1);
    #pragma unroll
    for (int nt = 0; nt < 4; nt++) {
      f32x4 s_acc = (f32x4){0.f, 0.f, 0.f, 0.f};
      #pragma unroll
      for (int kc = 0; kc < 4; kc++) {
        bf16x8 kf = *(const bf16x8*)(&Ksm[(nt * 16 + col) * KLD + kc * 32 + quad * 8]);
        s_acc = __builtin_amdgcn_mfma_f32_16x16x32_bf16(qf[kc], kf, s_acc, 0, 0, 0);
      }
      #pragma unroll
      for (int r = 0; r < 4; r++) p[nt][r] = s_acc[r];
    }
    __builtin_amdgcn_s_setprio(0);
    if (kt == my_qt) {  // diagonal tile: causal mask
      #pragma unroll
      for (int nt = 0; nt < 4; nt++) {
        int key = kt * 64 + nt * 16 + col;
        #pragma unroll
        for (int r = 0; r < 4; r++) {
          int rg = qrow + quad * 4 + r;
          if (key > rg) p[nt][r] = -1e30f;
        }
      }
    }
    // row max (tile) + defer-max: only rescale when max grew past threshold
    float mnew[4];
    float need = -1e30f;
    #pragma unroll
    for (int r = 0; r < 4; r++) {
      float mx = fmaxf(fmaxf(p[0][r], p[1][r]), fmaxf(p[2][r], p[3][r]));
      mx = fmaxf(mx, __shfl_xor(mx, 1));
      mx = fmaxf(mx, __shfl_xor(mx, 2));
      mx = fmaxf(mx, __shfl_xor(mx, 4));
      mx = fmaxf(mx, __shfl_xor(mx, 8));
      mnew[r] = mx;
      need = fmaxf(need, mx - m_i[r]);
    }
    if (__any(need > RESC_THR)) {   // wave-uniform branch
      #pragma unroll
      for (int r = 0; r < 4; r++) {
        float mn = fmaxf(m_i[r], mnew[r]);
        float alpha = exp2f(m_i[r] - mn);
        m_i[r] = mn;
        l_i[r] *= alpha;
        #pragma unroll
        for (int dt = 0; dt < 8; dt++) o[dt][r] *= alpha;
      }
    }
    float rsum[4] = {0.f, 0.f, 0.f, 0.f};
    #pragma unroll
    for (int nt = 0; nt < 4; nt++)
      #pragma unroll
      for (int r = 0; r < 4; r++) {
        float e = exp2f(p[nt][r] - m_i[r]);
        p[nt][r] = e;
        rsum[r] += e;
      }
    #pragma unroll
    for (int r = 0; r < 4; r++) {
      float rs = rsum[r];
      rs += __shfl_xor(rs, 1);
      rs += __shfl_xor(rs, 2);
      rs += __shfl_xor(rs, 4);
      rs += __shfl_xor(rs, 8);
      l_i[r] += rs;
    }

    // P: C-layout -> A-layout via wave-private LDS round trip
    #pragma unroll
    for (int nt = 0; nt < 4; nt++)
      #pragma unroll
      for (int r = 0; r < 4; r++)
        Pw[(quad * 4 + r) * VLD + nt * 16 + col] = f2bf(p[nt][r]);
    asm volatile("s_waitcnt lgkmcnt(0)" ::: "memory");  // wave-internal RAW
    bf16x8 pf[2];
    #pragma unroll
    for (int kc2 = 0; kc2 < 2; kc2++)
      pf[kc2] = *(const bf16x8*)(&Pw[col * VLD + kc2 * 32 + quad * 8]);

    // O += P V
    __builtin_amdgcn_s_setprio(1);
    #pragma unroll
    for (int dt = 0; dt < 8; dt++) {
      #pragma unroll
      for (int kc2 = 0; kc2 < 2; kc2++) {
        bf16x8 vf = *(const bf16x8*)(&Vsm[(dt * 16 + col) * VLD + kc2 * 32 + quad * 8]);
        o[dt] = __builtin_amdgcn_mfma_f32_16x16x32_bf16(pf[kc2], vf, o[dt], 0, 0, 0);
      }
    }
    __builtin_amdgcn_s_setprio(0);
    __syncthreads();
  }

  #pragma unroll
  for (int dt = 0; dt < 8; dt++) {
    int dcol = h * HD + dt * 16 + col;
    #pragma unroll
    for (int r = 0; r < 4; r++) {
      int rg = qrow + quad * 4 + r;
      ao[((size_t)(b * S_LEN) + rg) * DIM_ + dcol] = f2bf(o[dt][r] / l_i[r]);
    }
  }
}

extern "C" void kernel_launch(void* const* d_in, const int* in_sizes, int n_in,
                              void* d_out, int out_size, void* d_ws, size_t ws_size,
                              hipStream_t stream) {
  const float* x  = (const float*)d_in[0];
  const float* fc = (const float*)d_in[1];
  const float* fs = (const float*)d_in[2];
  const float* wq = (const float*)d_in[3];
  const float* wk = (const float*)d_in[4];
  const float* wv = (const float*)d_in[5];
  const float* wo = (const float*)d_in[6];
  float* out = (float*)d_out;

  char* ws = (char*)d_ws;
  const size_t MB = 1024 * 1024;
  unsigned short* xb    = (unsigned short*)(ws + 0 * MB);    // 4096x2048 bf16 (16 MiB)
  unsigned short* wqkvT = (unsigned short*)(ws + 16 * MB);   // 4096x2048      (16 MiB)
  unsigned short* woT   = (unsigned short*)(ws + 32 * MB);   // 2048x2048      (8 MiB)
  unsigned short* qb    = (unsigned short*)(ws + 40 * MB);   // 4096x2048      (16 MiB)
  unsigned short* kb    = (unsigned short*)(ws + 56 * MB);   // 4096x1024      (8 MiB)
  unsigned short* vT    = (unsigned short*)(ws + 64 * MB);   // (b,kvh,d,s)    (8 MiB)
  unsigned short* ao    = (unsigned short*)(ws + 72 * MB);   // 4096x2048      (16 MiB)

  // prep: convert x + transpose-convert all weights (one dispatch)
  k_prep<<<dim3(20480), dim3(256), 0, stream>>>(x, xb, wq, wk, wv, wo, wqkvT, woT);
  // fused QKV projection + RoPE (+q pre-scale) + V transpose
  k_gemm_bt<3><<<dim3(32, 32), dim3(256), 0, stream>>>(xb, wqkvT, (void*)qb, 4096, 2048, fc, fs, kb, vT);
  // attention: 512 blocks of 8 waves, 2-3 co-resident blocks/CU, balanced y-map
  k_attn<<<dim3(16, 32), dim3(512), 0, stream>>>(qb, kb, vT, ao);
  // output projection (f32 out)
  k_gemm_bt<1><<<dim3(16, 32), dim3(256), 0, stream>>>(ao, woT, (void*)out, 2048, 2048, nullptr, nullptr, nullptr, nullptr);
}

// Round 2
// 347.997 us; speedup vs baseline: 1.3555x; 1.3555x over previous
//
#include <hip/hip_runtime.h>
#include <cstdint>
#include <cstddef>

#define S_LEN 2048
#define DIM_   2048
#define NH   16
#define NKV  8
#define HD   128

typedef __attribute__((ext_vector_type(8))) __bf16 bf16x8;
typedef __attribute__((ext_vector_type(4))) float  f32x4;

typedef const __attribute__((address_space(1))) void* gptr_t;
typedef __attribute__((address_space(3))) void*       sptr_t;

static __device__ __forceinline__ float bf2f(unsigned short u) {
  union { unsigned int i; float f; } v; v.i = ((unsigned int)u) << 16; return v.f;
}
static __device__ __forceinline__ unsigned short f2bf(float f) {
  union { float f; unsigned int i; } v; v.f = f;
  unsigned int u = v.i;
  unsigned int r = (u + 0x7FFFu + ((u >> 16) & 1u)) >> 16;
  return (unsigned short)r;
}

// scale(1/sqrt(128)) * log2(e) — folded into q so softmax uses exp2 directly
#define QSCALE 0.12751744f
// defer-max threshold (T13): 8 in ln-domain -> 8*log2(e) in exp2-domain
#define RESC_THR 11.542f

// ---------------- prep: x->bf16 convert + 4 weight transpose-converts ----------------
__global__ void k_prep(const float* __restrict__ x, unsigned short* __restrict__ xb,
                       const float* __restrict__ wq, const float* __restrict__ wk,
                       const float* __restrict__ wv, const float* __restrict__ wo,
                       unsigned short* __restrict__ wqkvT, unsigned short* __restrict__ woT) {
  int bid = blockIdx.x;
  if (bid < 8192) {
    int i = bid * 256 + threadIdx.x;
    float4 v = ((const float4*)x)[i];
    ushort4 o; o.x = f2bf(v.x); o.y = f2bf(v.y); o.z = f2bf(v.z); o.w = f2bf(v.w);
    ((ushort4*)xb)[i] = o;
    return;
  }
  bid -= 8192;
  const float* src; unsigned short* dst; int N, ntx;
  if (bid < 4096)      { src = wq; dst = wqkvT;                       N = 2048; ntx = 64; }
  else if (bid < 6144) { bid -= 4096; src = wk; dst = wqkvT + (size_t)2048 * 2048; N = 1024; ntx = 32; }
  else if (bid < 8192) { bid -= 6144; src = wv; dst = wqkvT + (size_t)3072 * 2048; N = 1024; ntx = 32; }
  else                 { bid -= 8192; src = wo; dst = woT;            N = 2048; ntx = 64; }
  const int K = 2048;
  __shared__ float tile[32][33];
  int lx = threadIdx.x & 31, ly = threadIdx.x >> 5; // 32 x 8
  int r0 = (bid / ntx) * 32, c0 = (bid % ntx) * 32;
  #pragma unroll
  for (int r = 0; r < 32; r += 8)
    tile[ly + r][lx] = src[(size_t)(r0 + ly + r) * N + c0 + lx];
  __syncthreads();
  #pragma unroll
  for (int r = 0; r < 32; r += 8)
    dst[(size_t)(c0 + ly + r) * K + r0 + lx] = f2bf(tile[lx][ly + r]);
}

// ------------- GEMM: C(MxN) = A(MxK) * BT(NxK)^T, bf16 in, fp32 acc -------------
// BK=64, XOR-swizzled LDS via source permutation (conflict-free, measured 0).
// __launch_bounds__(256,2): VGPR cap 256 so all fragments stay live.
// MODE 1: store f32 natural C[m][n]
// MODE 3: fused QKV epilogue (q+RoPE*QSCALE | k+RoPE | v transposed).
template<int MODE>
__global__ __launch_bounds__(256, 2) void k_gemm_bt(
    const unsigned short* __restrict__ A, const unsigned short* __restrict__ BT,
    void* __restrict__ C, int N, int K,
    const float* __restrict__ fc, const float* __restrict__ fs,
    unsigned short* __restrict__ kb, unsigned short* __restrict__ vb) {
  __shared__ __align__(16) unsigned short Asm[128 * 64];
  __shared__ __align__(16) unsigned short Bsm[128 * 64];
  const int t = threadIdx.x;
  const int lane = t & 63, w = t >> 6;
  const int wm = (w >> 1) * 64, wn = (w & 1) * 64;
  const int col = lane & 15, quad = lane >> 4;
  const int m0 = blockIdx.y * 128, n0 = blockIdx.x * 128;

  f32x4 acc[4][4];
  #pragma unroll
  for (int i = 0; i < 4; i++)
    #pragma unroll
    for (int j = 0; j < 4; j++) acc[i][j] = (f32x4){0.f, 0.f, 0.f, 0.f};

  for (int kk = 0; kk < K; kk += 64) {
    #pragma unroll
    for (int r = 0; r < 4; ++r) {
      int c = t + r * 256;
      int c0 = (t & ~63) + r * 256;   // wave-uniform chunk base
      int row = c >> 3;
      int kcs = (c & 7) ^ (row & 7);  // source permutation = target swizzle
      const unsigned short* gA = A + (size_t)(m0 + row) * K + kk + kcs * 8;
      const unsigned short* gB = BT + (size_t)(n0 + row) * K + kk + kcs * 8;
      __builtin_amdgcn_global_load_lds((gptr_t)gA, (sptr_t)(&Asm[c0 * 8]), 16, 0, 0);
      __builtin_amdgcn_global_load_lds((gptr_t)gB, (sptr_t)(&Bsm[c0 * 8]), 16, 0, 0);
    }
    __syncthreads();
    #pragma unroll
    for (int kc2 = 0; kc2 < 2; kc2++) {
      bf16x8 af[4], bf[4];
      #pragma unroll
      for (int mi = 0; mi < 4; mi++) {
        int rowA = wm + mi * 16 + col;
        af[mi] = *(const bf16x8*)(&Asm[rowA * 64 + (((kc2 * 4 + quad) ^ (col & 7)) * 8)]);
      }
      #pragma unroll
      for (int ni = 0; ni < 4; ni++) {
        int rowB = wn + ni * 16 + col;
        bf[ni] = *(const bf16x8*)(&Bsm[rowB * 64 + (((kc2 * 4 + quad) ^ (col & 7)) * 8)]);
      }
      #pragma unroll
      for (int mi = 0; mi < 4; mi++)
        #pragma unroll
        for (int ni = 0; ni < 4; ni++)
          acc[mi][ni] = __builtin_amdgcn_mfma_f32_16x16x32_bf16(af[mi], bf[ni], acc[mi][ni], 0, 0, 0);
    }
    __syncthreads();
  }

  #pragma unroll
  for (int mi = 0; mi < 4; mi++) {
    int row_base = m0 + wm + mi * 16 + quad * 4;
    #pragma unroll
    for (int ni = 0; ni < 4; ni++) {
      int col_g = n0 + wn + ni * 16 + col;
      if (MODE == 1) {
        float* O = (float*)C;
        #pragma unroll
        for (int r = 0; r < 4; r++) O[(size_t)(row_base + r) * N + col_g] = acc[mi][ni][r];
      } else {  // MODE 3
        int region = col_g >> 10;  // 0,1: q ; 2: k ; 3: v
        if (region < 3) {
          int ri = (col_g & 127) >> 1;
          float sgn = (col_g & 1) ? 1.f : -1.f;
          unsigned short* qO = (unsigned short*)C;
          #pragma unroll
          for (int r = 0; r < 4; r++) {
            int row = row_base + r;
            int s = row & (S_LEN - 1);
            float cv = fc[s * 64 + ri], sv = fs[s * 64 + ri];
            float val = acc[mi][ni][r];
            float other = __shfl_xor(val, 1);
            float res = val * cv + sgn * other * sv;
            if (region < 2) qO[(size_t)row * 2048 + col_g] = f2bf(res * QSCALE);
            else            kb[(size_t)row * 1024 + (col_g - 2048)] = f2bf(res);
          }
        } else {
          int n_local = col_g - 3072;
          int b = row_base >> 11, s = row_base & (S_LEN - 1);
          int kvh = n_local >> 7, d = n_local & (HD - 1);
          ushort4 o4;
          o4.x = f2bf(acc[mi][ni][0]); o4.y = f2bf(acc[mi][ni][1]);
          o4.z = f2bf(acc[mi][ni][2]); o4.w = f2bf(acc[mi][ni][3]);
          *(ushort4*)(&vb[((size_t)((b * NKV + kvh) * HD + d)) * S_LEN + s]) = o4;
        }
      }
    }
  }
}

// ---------------- Flash attention, causal, GQA-shared K/V ----------------
// 512-thread blocks (8 waves = 2 heads x 4 waves), ONE q-tile per block.
// LDS 53 KB -> 3 blocks co-resident per CU (3 x 54272 = 162816 <= 163840);
// co-resident blocks are phase-decorrelated so one block's QK/PV MFMAs overlap
// another's softmax/staging latency. Causal range is wave-uniform (nkt = y+1).
// Balanced dispatch: yi<16 ? yi : 47-yi pairs long/short tiles (sum = 33).
// __launch_bounds__(512, 3): VGPR cap >= ~85 under either arg semantics.
// ROUND-1 LESSON: (512, 6) was interpreted as 6 BLOCKS/CU -> 40-VGPR cap ->
// o[8]/qf[4] accumulators spilled to scratch -> 225 MB of spill writes, 2x
// slower. Do NOT tighten this bound below 3.
#define KLD 136   // 128 + 8 (row-to-row bank offset 4 -> conflict-free frags)
#define VLD 72    // 64 + 8
__global__ __launch_bounds__(512, 3) void k_attn(
    const unsigned short* __restrict__ q, const unsigned short* __restrict__ k,
    const unsigned short* __restrict__ vT, unsigned short* __restrict__ ao) {
  __shared__ __align__(16) unsigned short Ksm[64 * KLD];       // 17408 B
  __shared__ __align__(16) unsigned short Vsm[128 * VLD];      // 18432 B
  __shared__ __align__(16) unsigned short Psm[8 * 16 * VLD];   // 18432 B
  const int t = threadIdx.x;
  const int lane = t & 63, w = t >> 6;        // 8 waves
  const int col = lane & 15, quad = lane >> 4;
  const int g = blockIdx.x;                   // b*NKV + kvh
  const int b = g >> 3, kvh = g & 7;
  const int h = kvh * 2 + (w >> 2);           // waves 0-3: head 2g, 4-7: head 2g+1
  const int yi = blockIdx.y;                  // 0..31
  const int my_qt = (yi < 16) ? yi : 47 - yi; // balanced long/short pairing
  const int qrow = my_qt * 64 + (w & 3) * 16; // this wave's 16 query rows
  unsigned short* Pw = &Psm[w * 16 * VLD];

  bf16x8 qf[4];
  const size_t qbase = ((size_t)(b * S_LEN) + qrow + col) * DIM_ + h * HD;
  #pragma unroll
  for (int kc = 0; kc < 4; kc++) qf[kc] = *(const bf16x8*)(q + qbase + kc * 32 + quad * 8);

  f32x4 o[8];
  #pragma unroll
  for (int i = 0; i < 8; i++) o[i] = (f32x4){0.f, 0.f, 0.f, 0.f};
  float m_i[4] = {-1e30f, -1e30f, -1e30f, -1e30f};
  float l_i[4] = {0.f, 0.f, 0.f, 0.f};

  const int nkt = my_qt + 1;                  // wave-uniform causal range
  for (int kt = 0; kt < nkt; ++kt) {
    // stage K tile (64 keys x 128 d) and V^T tile (128 d x 64 keys):
    // 2 uint4 per thread per matrix (512 threads)
    #pragma unroll
    for (int cc = 0; cc < 2; cc++) {
      int c = t + cc * 512;
      int i = c >> 4, dc = c & 15;
      *(uint4*)(&Ksm[i * KLD + dc * 8]) =
          *(const uint4*)(k + ((size_t)(b * S_LEN + kt * 64 + i)) * (NKV * HD) + kvh * HD + dc * 8);
    }
    #pragma unroll
    for (int cc = 0; cc < 2; cc++) {
      int c = t + cc * 512;
      int d = c >> 3, kc2 = c & 7;
      *(uint4*)(&Vsm[d * VLD + kc2 * 8]) =
          *(const uint4*)(vT + ((size_t)((b * NKV + kvh) * HD + d)) * S_LEN + kt * 64 + kc2 * 8);
    }
    __syncthreads();

    float p[4][4];
    __builtin_amdgcn_s_setprio(1);
    #pragma unroll
    for (int nt = 0; nt < 4; nt++) {
      f32x4 s_acc = (f32x4){0.f, 0.f, 0.f, 0.f};
      #pragma unroll
      for (int kc = 0; kc < 4; kc++) {
        bf16x8 kf = *(const bf16x8*)(&Ksm[(nt * 16 + col) * KLD + kc * 32 + quad * 8]);
        s_acc = __builtin_amdgcn_mfma_f32_16x16x32_bf16(qf[kc], kf, s_acc, 0, 0, 0);
      }
      #pragma unroll
      for (int r = 0; r < 4; r++) p[nt][r] = s_acc[r];
    }
    __builtin_amdgcn_s_setprio(0);
    if (kt == my_qt) {  // diagonal tile: causal mask
      #pragma unroll
      for (int nt = 0; nt < 4; nt++) {
        int key = kt * 64 + nt * 16 + col;
        #pragma unroll
        for (int r = 0; r < 4; r++) {
          int rg = qrow + quad * 4 + r;
          if (key > rg) p[nt][r] = -1e30f;
        }
      }
    }
    // row max (tile) + defer-max: only rescale when max grew past threshold
    float mnew[4];
    float need = -1e30f;
    #pragma unroll
    for (int r = 0; r < 4; r++) {
      float mx = fmaxf(fmaxf(p[0][r], p[1][r]), fmaxf(p[2][r], p[3][r]));
      mx = fmaxf(mx, __shfl_xor(mx, 1));
      mx = fmaxf(mx, __shfl_xor(mx, 2));
      mx = fmaxf(mx, __shfl_xor(mx, 4));
      mx = fmaxf(mx, __shfl_xor(mx, 8));
      mnew[r] = mx;
      need = fmaxf(need, mx - m_i[r]);
    }
    if (__any(need > RESC_THR)) {   // wave-uniform branch
      #pragma unroll
      for (int r = 0; r < 4; r++) {
        float mn = fmaxf(m_i[r], mnew[r]);
        float alpha = exp2f(m_i[r] - mn);
        m_i[r] = mn;
        l_i[r] *= alpha;
        #pragma unroll
        for (int dt = 0; dt < 8; dt++) o[dt][r] *= alpha;
      }
    }
    float rsum[4] = {0.f, 0.f, 0.f, 0.f};
    #pragma unroll
    for (int nt = 0; nt < 4; nt++)
      #pragma unroll
      for (int r = 0; r < 4; r++) {
        float e = exp2f(p[nt][r] - m_i[r]);
        p[nt][r] = e;
        rsum[r] += e;
      }
    #pragma unroll
    for (int r = 0; r < 4; r++) {
      float rs = rsum[r];
      rs += __shfl_xor(rs, 1);
      rs += __shfl_xor(rs, 2);
      rs += __shfl_xor(rs, 4);
      rs += __shfl_xor(rs, 8);
      l_i[r] += rs;
    }

    // P: C-layout -> A-layout via wave-private LDS round trip
    #pragma unroll
    for (int nt = 0; nt < 4; nt++)
      #pragma unroll
      for (int r = 0; r < 4; r++)
        Pw[(quad * 4 + r) * VLD + nt * 16 + col] = f2bf(p[nt][r]);
    asm volatile("s_waitcnt lgkmcnt(0)" ::: "memory");  // wave-internal RAW
    bf16x8 pf[2];
    #pragma unroll
    for (int kc2 = 0; kc2 < 2; kc2++)
      pf[kc2] = *(const bf16x8*)(&Pw[col * VLD + kc2 * 32 + quad * 8]);

    // O += P V
    __builtin_amdgcn_s_setprio(1);
    #pragma unroll
    for (int dt = 0; dt < 8; dt++) {
      #pragma unroll
      for (int kc2 = 0; kc2 < 2; kc2++) {
        bf16x8 vf = *(const bf16x8*)(&Vsm[(dt * 16 + col) * VLD + kc2 * 32 + quad * 8]);
        o[dt] = __builtin_amdgcn_mfma_f32_16x16x32_bf16(pf[kc2], vf, o[dt], 0, 0, 0);
      }
    }
    __builtin_amdgcn_s_setprio(0);
    __syncthreads();
  }

  #pragma unroll
  for (int dt = 0; dt < 8; dt++) {
    int dcol = h * HD + dt * 16 + col;
    #pragma unroll
    for (int r = 0; r < 4; r++) {
      int rg = qrow + quad * 4 + r;
      ao[((size_t)(b * S_LEN) + rg) * DIM_ + dcol] = f2bf(o[dt][r] / l_i[r]);
    }
  }
}

extern "C" void kernel_launch(void* const* d_in, const int* in_sizes, int n_in,
                              void* d_out, int out_size, void* d_ws, size_t ws_size,
                              hipStream_t stream) {
  const float* x  = (const float*)d_in[0];
  const float* fc = (const float*)d_in[1];
  const float* fs = (const float*)d_in[2];
  const float* wq = (const float*)d_in[3];
  const float* wk = (const float*)d_in[4];
  const float* wv = (const float*)d_in[5];
  const float* wo = (const float*)d_in[6];
  float* out = (float*)d_out;

  char* ws = (char*)d_ws;
  const size_t MB = 1024 * 1024;
  unsigned short* xb    = (unsigned short*)(ws + 0 * MB);    // 4096x2048 bf16 (16 MiB)
  unsigned short* wqkvT = (unsigned short*)(ws + 16 * MB);   // 4096x2048      (16 MiB)
  unsigned short* woT   = (unsigned short*)(ws + 32 * MB);   // 2048x2048      (8 MiB)
  unsigned short* qb    = (unsigned short*)(ws + 40 * MB);   // 4096x2048      (16 MiB)
  unsigned short* kb    = (unsigned short*)(ws + 56 * MB);   // 4096x1024      (8 MiB)
  unsigned short* vT    = (unsigned short*)(ws + 64 * MB);   // (b,kvh,d,s)    (8 MiB)
  unsigned short* ao    = (unsigned short*)(ws + 72 * MB);   // 4096x2048      (16 MiB)

  // prep: convert x + transpose-convert all weights (one dispatch)
  k_prep<<<dim3(20480), dim3(256), 0, stream>>>(x, xb, wq, wk, wv, wo, wqkvT, woT);
  // fused QKV projection + RoPE (+q pre-scale) + V transpose
  k_gemm_bt<3><<<dim3(32, 32), dim3(256), 0, stream>>>(xb, wqkvT, (void*)qb, 4096, 2048, fc, fs, kb, vT);
  // attention: 512 blocks of 8 waves, 3 co-resident blocks/CU, balanced y-map
  k_attn<<<dim3(16, 32), dim3(512), 0, stream>>>(qb, kb, vT, ao);
  // output projection (f32 out)
  k_gemm_bt<1><<<dim3(16, 32), dim3(256), 0, stream>>>(ao, woT, (void*)out, 2048, 2048, nullptr, nullptr, nullptr, nullptr);
}

// Round 3
// 335.853 us; speedup vs baseline: 1.4045x; 1.0362x over previous
//
#include <hip/hip_runtime.h>
#include <cstdint>
#include <cstddef>

#define S_LEN 2048
#define DIM_   2048
#define NH   16
#define NKV  8
#define HD   128

typedef __attribute__((ext_vector_type(8))) __bf16 bf16x8;
typedef __attribute__((ext_vector_type(4))) float  f32x4;

typedef const __attribute__((address_space(1))) void* gptr_t;
typedef __attribute__((address_space(3))) void*       sptr_t;

static __device__ __forceinline__ float bf2f(unsigned short u) {
  union { unsigned int i; float f; } v; v.i = ((unsigned int)u) << 16; return v.f;
}
static __device__ __forceinline__ unsigned short f2bf(float f) {
  union { float f; unsigned int i; } v; v.f = f;
  unsigned int u = v.i;
  unsigned int r = (u + 0x7FFFu + ((u >> 16) & 1u)) >> 16;
  return (unsigned short)r;
}

// scale(1/sqrt(128)) * log2(e) — folded into q so softmax uses exp2 directly
#define QSCALE 0.12751744f
// defer-max threshold (T13): 8 in ln-domain -> 8*log2(e) in exp2-domain
#define RESC_THR 11.542f

// ---------------- prep: x->bf16 convert + 4 weight transpose-converts ----------------
__global__ void k_prep(const float* __restrict__ x, unsigned short* __restrict__ xb,
                       const float* __restrict__ wq, const float* __restrict__ wk,
                       const float* __restrict__ wv, const float* __restrict__ wo,
                       unsigned short* __restrict__ wqkvT, unsigned short* __restrict__ woT) {
  int bid = blockIdx.x;
  if (bid < 8192) {
    int i = bid * 256 + threadIdx.x;
    float4 v = ((const float4*)x)[i];
    ushort4 o; o.x = f2bf(v.x); o.y = f2bf(v.y); o.z = f2bf(v.z); o.w = f2bf(v.w);
    ((ushort4*)xb)[i] = o;
    return;
  }
  bid -= 8192;
  const float* src; unsigned short* dst; int N, ntx;
  if (bid < 4096)      { src = wq; dst = wqkvT;                       N = 2048; ntx = 64; }
  else if (bid < 6144) { bid -= 4096; src = wk; dst = wqkvT + (size_t)2048 * 2048; N = 1024; ntx = 32; }
  else if (bid < 8192) { bid -= 6144; src = wv; dst = wqkvT + (size_t)3072 * 2048; N = 1024; ntx = 32; }
  else                 { bid -= 8192; src = wo; dst = woT;            N = 2048; ntx = 64; }
  const int K = 2048;
  __shared__ float tile[32][33];
  int lx = threadIdx.x & 31, ly = threadIdx.x >> 5; // 32 x 8
  int r0 = (bid / ntx) * 32, c0 = (bid % ntx) * 32;
  #pragma unroll
  for (int r = 0; r < 32; r += 8)
    tile[ly + r][lx] = src[(size_t)(r0 + ly + r) * N + c0 + lx];
  __syncthreads();
  #pragma unroll
  for (int r = 0; r < 32; r += 8)
    dst[(size_t)(c0 + ly + r) * K + r0 + lx] = f2bf(tile[lx][ly + r]);
}

// ------------- GEMM: C(MxN) = A(MxK) * BT(NxK)^T, bf16 in, fp32 acc -------------
// BK=64, XOR-swizzled LDS via source permutation (conflict-free, measured 0).
// __launch_bounds__(256,2): VGPR cap 256 so all fragments stay live.
// MODE 1: store f32 natural C[m][n]
// MODE 3: fused QKV epilogue (q+RoPE*QSCALE | k+RoPE | v transposed).
template<int MODE>
__global__ __launch_bounds__(256, 2) void k_gemm_bt(
    const unsigned short* __restrict__ A, const unsigned short* __restrict__ BT,
    void* __restrict__ C, int N, int K,
    const float* __restrict__ fc, const float* __restrict__ fs,
    unsigned short* __restrict__ kb, unsigned short* __restrict__ vb) {
  __shared__ __align__(16) unsigned short Asm[128 * 64];
  __shared__ __align__(16) unsigned short Bsm[128 * 64];
  const int t = threadIdx.x;
  const int lane = t & 63, w = t >> 6;
  const int wm = (w >> 1) * 64, wn = (w & 1) * 64;
  const int col = lane & 15, quad = lane >> 4;
  const int m0 = blockIdx.y * 128, n0 = blockIdx.x * 128;

  f32x4 acc[4][4];
  #pragma unroll
  for (int i = 0; i < 4; i++)
    #pragma unroll
    for (int j = 0; j < 4; j++) acc[i][j] = (f32x4){0.f, 0.f, 0.f, 0.f};

  for (int kk = 0; kk < K; kk += 64) {
    #pragma unroll
    for (int r = 0; r < 4; ++r) {
      int c = t + r * 256;
      int c0 = (t & ~63) + r * 256;   // wave-uniform chunk base
      int row = c >> 3;
      int kcs = (c & 7) ^ (row & 7);  // source permutation = target swizzle
      const unsigned short* gA = A + (size_t)(m0 + row) * K + kk + kcs * 8;
      const unsigned short* gB = BT + (size_t)(n0 + row) * K + kk + kcs * 8;
      __builtin_amdgcn_global_load_lds((gptr_t)gA, (sptr_t)(&Asm[c0 * 8]), 16, 0, 0);
      __builtin_amdgcn_global_load_lds((gptr_t)gB, (sptr_t)(&Bsm[c0 * 8]), 16, 0, 0);
    }
    __syncthreads();
    #pragma unroll
    for (int kc2 = 0; kc2 < 2; kc2++) {
      bf16x8 af[4], bf[4];
      #pragma unroll
      for (int mi = 0; mi < 4; mi++) {
        int rowA = wm + mi * 16 + col;
        af[mi] = *(const bf16x8*)(&Asm[rowA * 64 + (((kc2 * 4 + quad) ^ (col & 7)) * 8)]);
      }
      #pragma unroll
      for (int ni = 0; ni < 4; ni++) {
        int rowB = wn + ni * 16 + col;
        bf[ni] = *(const bf16x8*)(&Bsm[rowB * 64 + (((kc2 * 4 + quad) ^ (col & 7)) * 8)]);
      }
      #pragma unroll
      for (int mi = 0; mi < 4; mi++)
        #pragma unroll
        for (int ni = 0; ni < 4; ni++)
          acc[mi][ni] = __builtin_amdgcn_mfma_f32_16x16x32_bf16(af[mi], bf[ni], acc[mi][ni], 0, 0, 0);
    }
    __syncthreads();
  }

  #pragma unroll
  for (int mi = 0; mi < 4; mi++) {
    int row_base = m0 + wm + mi * 16 + quad * 4;
    #pragma unroll
    for (int ni = 0; ni < 4; ni++) {
      int col_g = n0 + wn + ni * 16 + col;
      if (MODE == 1) {
        float* O = (float*)C;
        #pragma unroll
        for (int r = 0; r < 4; r++) O[(size_t)(row_base + r) * N + col_g] = acc[mi][ni][r];
      } else {  // MODE 3
        int region = col_g >> 10;  // 0,1: q ; 2: k ; 3: v
        if (region < 3) {
          int ri = (col_g & 127) >> 1;
          float sgn = (col_g & 1) ? 1.f : -1.f;
          unsigned short* qO = (unsigned short*)C;
          #pragma unroll
          for (int r = 0; r < 4; r++) {
            int row = row_base + r;
            int s = row & (S_LEN - 1);
            float cv = fc[s * 64 + ri], sv = fs[s * 64 + ri];
            float val = acc[mi][ni][r];
            float other = __shfl_xor(val, 1);
            float res = val * cv + sgn * other * sv;
            if (region < 2) qO[(size_t)row * 2048 + col_g] = f2bf(res * QSCALE);
            else            kb[(size_t)row * 1024 + (col_g - 2048)] = f2bf(res);
          }
        } else {
          int n_local = col_g - 3072;
          int b = row_base >> 11, s = row_base & (S_LEN - 1);
          int kvh = n_local >> 7, d = n_local & (HD - 1);
          ushort4 o4;
          o4.x = f2bf(acc[mi][ni][0]); o4.y = f2bf(acc[mi][ni][1]);
          o4.z = f2bf(acc[mi][ni][2]); o4.w = f2bf(acc[mi][ni][3]);
          *(ushort4*)(&vb[((size_t)((b * NKV + kvh) * HD + d)) * S_LEN + s]) = o4;
        }
      }
    }
  }
}

// ---------------- Flash attention, causal, GQA-shared K/V ----------------
// 512-thread blocks (8 waves = 2 heads x 4 waves), ONE q-tile per block,
// grid (16,32) = 2 blocks/CU (yi-pairing: blocks bid and bid+256 land on the
// same CU and sum to 33 tiles). Round-3 restructure:
//  * SWAPPED QK^T: p = mfma(K, Q) so each lane owns one q-row (q = col).
//    Row max/sum = 15 lane-local ops + 2 shfl_xor (was 32 shfls/tile).
//    m_i/l_i are scalars per lane; exp2/mask lane-local. Only the (rare,
//    defer-max-gated) O-rescale and the final 1/l need a 4-shfl col->row move.
//  * ASYNC STAGING (T14): K(t+1) global loads issue before QK(t) compute,
//    V(t+1) loads after barrier 1; LDS writes overlap the OTHER matrix's
//    MFMA phase (K-writes during PV, V-writes during QK). Single-buffered
//    K/V is safe: QK only reads K, PV only reads V, and the two existing
//    barriers separate writers from readers.
//  * P round trip: 4x ds_write_b64 (packed bf16 pairs) instead of 16x b16.
// ROUND-1 LESSON: __launch_bounds__ 2nd arg acts as BLOCKS/CU here; (512,6)
// capped VGPR at 40 -> accumulator spill -> 225 MB scratch traffic. Grid
// gives exactly 2 blocks/CU -> (512,2) = 128-VGPR cap. Watch WRITE_SIZE
// (~16 MB = no spill).
#define KLD 136   // 128 + 8 (row-to-row bank offset 4 -> conflict-free frags)
#define VLD 72    // 64 + 8
__global__ __launch_bounds__(512, 2) void k_attn(
    const unsigned short* __restrict__ q, const unsigned short* __restrict__ k,
    const unsigned short* __restrict__ vT, unsigned short* __restrict__ ao) {
  __shared__ __align__(16) unsigned short Ksm[64 * KLD];       // 17408 B
  __shared__ __align__(16) unsigned short Vsm[128 * VLD];      // 18432 B
  __shared__ __align__(16) unsigned short Psm[8 * 16 * VLD];   // 18432 B
  const int t = threadIdx.x;
  const int lane = t & 63, w = t >> 6;        // 8 waves
  const int col = lane & 15, quad = lane >> 4;
  const int g = blockIdx.x;                   // b*NKV + kvh
  const int b = g >> 3, kvh = g & 7;
  const int h = kvh * 2 + (w >> 2);           // waves 0-3: head 2g, 4-7: head 2g+1
  const int yi = blockIdx.y;                  // 0..31
  const int my_qt = (yi < 16) ? yi : 47 - yi; // balanced long/short pairing
  const int qrow = my_qt * 64 + (w & 3) * 16; // this wave's 16 query rows
  unsigned short* Pw = &Psm[w * 16 * VLD];

  // staging addresses (per thread): 2 uint4 for K, 2 uint4 for V
  const int ki0 = t >> 4,        kdc = t & 15;         // K row / d-chunk
  const int ki1 = (t + 512) >> 4;
  const int vd0 = t >> 3,        vkc = t & 7;          // V d-row / key-chunk
  const int vd1 = (t + 512) >> 3;
  const unsigned short* kgp = k + (size_t)(b * S_LEN) * (NKV * HD) + kvh * HD + kdc * 8;
  const unsigned short* vgp = vT + ((size_t)(b * NKV + kvh) * HD) * S_LEN + vkc * 8;

  bf16x8 qf[4];
  const size_t qbase = ((size_t)(b * S_LEN) + qrow + col) * DIM_ + h * HD;
  #pragma unroll
  for (int kc = 0; kc < 4; kc++) qf[kc] = *(const bf16x8*)(q + qbase + kc * 32 + quad * 8);

  f32x4 o[8];
  #pragma unroll
  for (int i = 0; i < 8; i++) o[i] = (f32x4){0.f, 0.f, 0.f, 0.f};
  float m_i = -1e30f;   // running max for q-row (qrow + col)
  float l_i = 0.f;      // running denom for q-row (qrow + col)

  const int nkt = my_qt + 1;                  // wave-uniform causal range

  // prologue: stage tile 0
  {
    uint4 kr0 = *(const uint4*)(kgp + (size_t)ki0 * (NKV * HD));
    uint4 kr1 = *(const uint4*)(kgp + (size_t)ki1 * (NKV * HD));
    uint4 vr0 = *(const uint4*)(vgp + (size_t)vd0 * S_LEN);
    uint4 vr1 = *(const uint4*)(vgp + (size_t)vd1 * S_LEN);
    *(uint4*)(&Ksm[ki0 * KLD + kdc * 8]) = kr0;
    *(uint4*)(&Ksm[ki1 * KLD + kdc * 8]) = kr1;
    *(uint4*)(&Vsm[vd0 * VLD + vkc * 8]) = vr0;
    *(uint4*)(&Vsm[vd1 * VLD + vkc * 8]) = vr1;
  }
  __syncthreads();

  for (int kt = 0; kt < nkt; ++kt) {
    const bool more = (kt + 1 < nkt);         // block-uniform
    uint4 kr0, kr1, vr0, vr1;
    if (more) {                               // issue K(t+1) early: latency hides under QK+softmax
      kr0 = *(const uint4*)(kgp + (size_t)((kt + 1) * 64 + ki0) * (NKV * HD));
      kr1 = *(const uint4*)(kgp + (size_t)((kt + 1) * 64 + ki1) * (NKV * HD));
    }

    // ---- QK^T, swapped operands: p[nt][r] = P[key = kt*64+nt*16+quad*4+r][q = col]
    float p[4][4];
    __builtin_amdgcn_s_setprio(1);
    #pragma unroll
    for (int nt = 0; nt < 4; nt++) {
      f32x4 s_acc = (f32x4){0.f, 0.f, 0.f, 0.f};
      #pragma unroll
      for (int kc = 0; kc < 4; kc++) {
        bf16x8 kf = *(const bf16x8*)(&Ksm[(nt * 16 + col) * KLD + kc * 32 + quad * 8]);
        s_acc = __builtin_amdgcn_mfma_f32_16x16x32_bf16(kf, qf[kc], s_acc, 0, 0, 0);
      }
      #pragma unroll
      for (int r = 0; r < 4; r++) p[nt][r] = s_acc[r];
    }
    __builtin_amdgcn_s_setprio(0);

    if (kt == my_qt) {  // diagonal tile: causal mask (q = qrow+col, key per reg)
      const int qglob = qrow + col;
      #pragma unroll
      for (int nt = 0; nt < 4; nt++)
        #pragma unroll
        for (int r = 0; r < 4; r++)
          if (kt * 64 + nt * 16 + quad * 4 + r > qglob) p[nt][r] = -1e30f;
    }

    // ---- softmax for this lane's q-row: 15 local fmax + 2 shfl
    float mx = fmaxf(fmaxf(fmaxf(p[0][0], p[0][1]), fmaxf(p[0][2], p[0][3])),
                     fmaxf(fmaxf(p[1][0], p[1][1]), fmaxf(p[1][2], p[1][3])));
    mx = fmaxf(mx, fmaxf(fmaxf(fmaxf(p[2][0], p[2][1]), fmaxf(p[2][2], p[2][3])),
                         fmaxf(fmaxf(p[3][0], p[3][1]), fmaxf(p[3][2], p[3][3]))));
    mx = fmaxf(mx, __shfl_xor(mx, 16));
    mx = fmaxf(mx, __shfl_xor(mx, 32));
    if (__any(mx - m_i > RESC_THR)) {   // defer-max (T13): rare
      float mn = fmaxf(m_i, mx);
      float alpha = exp2f(m_i - mn);
      m_i = mn; l_i *= alpha;
      float ar[4];
      #pragma unroll
      for (int r = 0; r < 4; r++) ar[r] = __shfl(alpha, quad * 4 + r);
      #pragma unroll
      for (int dt = 0; dt < 8; dt++)
        #pragma unroll
        for (int r = 0; r < 4; r++) o[dt][r] *= ar[r];
    }
    float rs = 0.f;
    #pragma unroll
    for (int nt = 0; nt < 4; nt++)
      #pragma unroll
      for (int r = 0; r < 4; r++) {
        float e = exp2f(p[nt][r] - m_i);
        p[nt][r] = e;
        rs += e;
      }
    rs += __shfl_xor(rs, 16);
    rs += __shfl_xor(rs, 32);
    l_i += rs;

    // ---- P -> Pw (A-layout directly: Pw[q][key]), 4x packed b64 writes
    #pragma unroll
    for (int nt = 0; nt < 4; nt++) {
      unsigned int w0 = (unsigned int)f2bf(p[nt][0]) | ((unsigned int)f2bf(p[nt][1]) << 16);
      unsigned int w1 = (unsigned int)f2bf(p[nt][2]) | ((unsigned int)f2bf(p[nt][3]) << 16);
      uint2 pk; pk.x = w0; pk.y = w1;
      *(uint2*)(&Pw[col * VLD + nt * 16 + quad * 4]) = pk;
    }

    __syncthreads();   // B1: all waves done reading Ksm (and Pw writes drained)

    if (more) {        // K(t+1) -> LDS (overlaps PV), issue V(t+1) loads
      *(uint4*)(&Ksm[ki0 * KLD + kdc * 8]) = kr0;
      *(uint4*)(&Ksm[ki1 * KLD + kdc * 8]) = kr1;
      vr0 = *(const uint4*)(vgp + (size_t)vd0 * S_LEN + (kt + 1) * 64);
      vr1 = *(const uint4*)(vgp + (size_t)vd1 * S_LEN + (kt + 1) * 64);
    }

    bf16x8 pf[2];
    #pragma unroll
    for (int kc2 = 0; kc2 < 2; kc2++)
      pf[kc2] = *(const bf16x8*)(&Pw[col * VLD + kc2 * 32 + quad * 8]);

    // ---- O += P V
    __builtin_amdgcn_s_setprio(1);
    #pragma unroll
    for (int dt = 0; dt < 8; dt++) {
      #pragma unroll
      for (int kc2 = 0; kc2 < 2; kc2++) {
        bf16x8 vf = *(const bf16x8*)(&Vsm[(dt * 16 + col) * VLD + kc2 * 32 + quad * 8]);
        o[dt] = __builtin_amdgcn_mfma_f32_16x16x32_bf16(pf[kc2], vf, o[dt], 0, 0, 0);
      }
    }
    __builtin_amdgcn_s_setprio(0);

    __syncthreads();   // B2: all waves done reading Vsm; Ksm(t+1) visible

    if (more) {        // V(t+1) -> LDS (overlaps next QK)
      *(uint4*)(&Vsm[vd0 * VLD + vkc * 8]) = vr0;
      *(uint4*)(&Vsm[vd1 * VLD + vkc * 8]) = vr1;
    }
  }

  // epilogue: 1/l for this lane's four q-rows (col -> row permute, once)
  float linv[4];
  #pragma unroll
  for (int r = 0; r < 4; r++) linv[r] = 1.f / __shfl(l_i, quad * 4 + r);
  #pragma unroll
  for (int dt = 0; dt < 8; dt++) {
    int dcol = h * HD + dt * 16 + col;
    #pragma unroll
    for (int r = 0; r < 4; r++) {
      int rg = qrow + quad * 4 + r;
      ao[((size_t)(b * S_LEN) + rg) * DIM_ + dcol] = f2bf(o[dt][r] * linv[r]);
    }
  }
}

extern "C" void kernel_launch(void* const* d_in, const int* in_sizes, int n_in,
                              void* d_out, int out_size, void* d_ws, size_t ws_size,
                              hipStream_t stream) {
  const float* x  = (const float*)d_in[0];
  const float* fc = (const float*)d_in[1];
  const float* fs = (const float*)d_in[2];
  const float* wq = (const float*)d_in[3];
  const float* wk = (const float*)d_in[4];
  const float* wv = (const float*)d_in[5];
  const float* wo = (const float*)d_in[6];
  float* out = (float*)d_out;

  char* ws = (char*)d_ws;
  const size_t MB = 1024 * 1024;
  unsigned short* xb    = (unsigned short*)(ws + 0 * MB);    // 4096x2048 bf16 (16 MiB)
  unsigned short* wqkvT = (unsigned short*)(ws + 16 * MB);   // 4096x2048      (16 MiB)
  unsigned short* woT   = (unsigned short*)(ws + 32 * MB);   // 2048x2048      (8 MiB)
  unsigned short* qb    = (unsigned short*)(ws + 40 * MB);   // 4096x2048      (16 MiB)
  unsigned short* kb    = (unsigned short*)(ws + 56 * MB);   // 4096x1024      (8 MiB)
  unsigned short* vT    = (unsigned short*)(ws + 64 * MB);   // (b,kvh,d,s)    (8 MiB)
  unsigned short* ao    = (unsigned short*)(ws + 72 * MB);   // 4096x2048      (16 MiB)

  // prep: convert x + transpose-convert all weights (one dispatch)
  k_prep<<<dim3(20480), dim3(256), 0, stream>>>(x, xb, wq, wk, wv, wo, wqkvT, woT);
  // fused QKV projection + RoPE (+q pre-scale) + V transpose
  k_gemm_bt<3><<<dim3(32, 32), dim3(256), 0, stream>>>(xb, wqkvT, (void*)qb, 4096, 2048, fc, fs, kb, vT);
  // attention: swapped-QK softmax + async staging, 2 blocks/CU
  k_attn<<<dim3(16, 32), dim3(512), 0, stream>>>(qb, kb, vT, ao);
  // output projection (f32 out)
  k_gemm_bt<1><<<dim3(16, 32), dim3(256), 0, stream>>>(ao, woT, (void*)out, 2048, 2048, nullptr, nullptr, nullptr, nullptr);
}